// Round 7
// baseline (220.246 us; speedup 1.0000x reference)
//
#include <hip/hip_runtime.h>

typedef __attribute__((ext_vector_type(8))) short short8;
typedef __attribute__((ext_vector_type(4))) short short4v;
typedef __attribute__((ext_vector_type(4))) float floatx4;
typedef __attribute__((ext_vector_type(16))) float floatx16;

#define GLOBAL_AS __attribute__((address_space(1)))
#define LDS_AS __attribute__((address_space(3)))

__device__ __forceinline__ short f2bs(float f) {
    // RNE float -> bf16 (as short). Inputs finite here.
    union { float f; unsigned u; } v; v.f = f;
    unsigned r = v.u + 0x7fffu + ((v.u >> 16) & 1u);
    return (short)(r >> 16);
}

#if __has_builtin(__builtin_amdgcn_cvt_pk_bf16_f32)
typedef __attribute__((ext_vector_type(2))) __bf16 bf16x2;
__device__ __forceinline__ unsigned pk2(float a, float b) {
    union { bf16x2 v; unsigned u; } u;
    u.v = __builtin_amdgcn_cvt_pk_bf16_f32(a, b);
    return u.u;
}
#else
__device__ __forceinline__ unsigned pk2(float a, float b) {
    union { float f; unsigned u; } x, y; x.f = a; y.f = b;
    return ((y.u + 0x8000u) & 0xffff0000u) | ((x.u + 0x8000u) >> 16);
}
#endif

// ---------------- cast fp32 -> bf16, weights only ----------------
__global__ __launch_bounds__(256) void cast_w(const float* __restrict__ Wq,
                                              const float* __restrict__ Wk,
                                              const float* __restrict__ Wv,
                                              short* __restrict__ wb) {
    int b = blockIdx.x;
    int t = threadIdx.x;
    int wz = b >> 10;
    const float* src = (wz == 0) ? Wq : (wz == 1) ? Wk : Wv;
    short* dst = wb + wz * (1 << 20);
    int idx = (b & 1023) * 1024 + t * 4;
    float4 v = *(const float4*)(src + idx);
    short4v o;
    o.x = f2bs(v.x); o.y = f2bs(v.y); o.z = f2bs(v.z); o.w = f2bs(v.w);
    *(short4v*)(dst + idx) = o;
}

// ---------------- QKV GEMM: BK=64, A staged from fp32 x directly (R5 structure) ----------------
// z=0 -> Q [b,h,n,d] pre-scaled by 0.125*log2(e); z=1 -> K [b,h,n,d]; z=2 -> V^T [b,h,d,n]
__global__ __launch_bounds__(256) void qkv_gemm(const float* __restrict__ x,
                                                const short* __restrict__ wb,
                                                short* __restrict__ qout,
                                                short* __restrict__ kout,
                                                short* __restrict__ vtout) {
    __shared__ short As[128 * 64];  // [m][k], 16B chunks XOR-swizzled: slot = chunk ^ (row&7)
    __shared__ short Bs[128 * 64];
    const int K = 1024;
    int tid = threadIdx.x;
    int lane = tid & 63;
    int wid = tid >> 6;
    int quad = lane >> 4;
    int l16 = lane & 15;
    int wm = (wid >> 1) * 64;
    int wn = (wid & 1) * 64;
    int bm = blockIdx.x * 128;
    int bn = blockIdx.y * 128;
    const short* W = wb + (size_t)blockIdx.z * K * 1024;

    floatx4 acc[4][4];
#pragma unroll
    for (int i = 0; i < 4; i++)
#pragma unroll
        for (int j = 0; j < 4; j++) acc[i][j] = (floatx4){0.f, 0.f, 0.f, 0.f};

    int srow = tid >> 3;                     // 0..31 (base row of this thread's chunks)
    int ssw = ((tid & 7) ^ (srow & 7)) * 8;  // swizzled SOURCE element offset within 64-elt row seg

    for (int kk = 0; kk < K; kk += 64) {
        __syncthreads();
        // A: fp32 x -> convert -> LDS (same swizzled slots as global_load_lds would use)
        float4 av[8];
#pragma unroll
        for (int l = 0; l < 4; l++) {
            const float* gx = x + (size_t)(bm + srow + l * 32) * K + kk + ssw;
            av[2 * l] = *(const float4*)gx;
            av[2 * l + 1] = *(const float4*)(gx + 4);
        }
#pragma unroll
        for (int l = 0; l < 4; l++) {
            int4 wv;
            wv.x = pk2(av[2 * l].x, av[2 * l].y);
            wv.y = pk2(av[2 * l].z, av[2 * l].w);
            wv.z = pk2(av[2 * l + 1].x, av[2 * l + 1].y);
            wv.w = pk2(av[2 * l + 1].z, av[2 * l + 1].w);
            *(int4*)(As + tid * 8 + l * 2048) = wv;
        }
        // B: bf16 W via async global->LDS
#pragma unroll
        for (int l = 0; l < 4; l++) {
            const short* g = W + (size_t)(bn + srow + l * 32) * K + kk + ssw;
            __builtin_amdgcn_global_load_lds((const GLOBAL_AS void*)g,
                                             (LDS_AS void*)(Bs + tid * 8 + l * 2048), 16, 0, 0);
        }
        __syncthreads();

#pragma unroll
        for (int s = 0; s < 2; s++) {
            int slot = ((s * 4 + quad) ^ (l16 & 7)) * 8;
            short8 af[4], bf[4];
#pragma unroll
            for (int i = 0; i < 4; i++)
                af[i] = *(const short8*)(As + (wm + i * 16 + l16) * 64 + slot);
#pragma unroll
            for (int j = 0; j < 4; j++)
                bf[j] = *(const short8*)(Bs + (wn + j * 16 + l16) * 64 + slot);
#pragma unroll
            for (int i = 0; i < 4; i++)
#pragma unroll
                for (int j = 0; j < 4; j++)
                    acc[i][j] = __builtin_amdgcn_mfma_f32_16x16x32_bf16(af[i], bf[j], acc[i][j], 0, 0, 0);
        }
    }

    // Epilogue (R5 layouts). C/D: col = l16, row = quad*4 + r.
    if (blockIdx.z == 2) {
        // V^T [b,h,d,n]: reg-quad = 4 consecutive seq -> packed b64 stores
#pragma unroll
        for (int i = 0; i < 4; i++) {
#pragma unroll
            for (int j = 0; j < 4; j++) {
                int m = bm + wm + i * 16 + quad * 4;
                int c = bn + wn + j * 16 + l16;
                int b = m >> 11, nn = m & 2047, h = c >> 6, dd = c & 63;
                int2 wv;
                wv.x = pk2(acc[i][j][0], acc[i][j][1]);
                wv.y = pk2(acc[i][j][2], acc[i][j][3]);
                *(int2*)(vtout + ((size_t)(b * 16 + h) * 64 + dd) * 2048 + nn) = wv;
            }
        }
    } else {
        // Q/K [b,h,n,d]: 16-lane-contiguous u16 stores (coalesced 32B segments)
        short* dst = (blockIdx.z == 0) ? qout : kout;
        float qs = (blockIdx.z == 0) ? 0.180336881f : 1.0f;  // 0.125*log2(e) folded into Q
#pragma unroll
        for (int i = 0; i < 4; i++) {
#pragma unroll
            for (int j = 0; j < 4; j++) {
#pragma unroll
                for (int r = 0; r < 4; r++) {
                    int m = bm + wm + i * 16 + quad * 4 + r;
                    int c = bn + wn + j * 16 + l16;
                    dst[((size_t)((m >> 11) * 16 + (c >> 6)) * 2048 + (m & 2047)) * 64 + (c & 63)] =
                        f2bs(acc[i][j][r] * qs);
                }
            }
        }
    }
}

// ---------------- Flash attention: 32x32x16 MFMA, S^T + O^T tricks (R6, unchanged) ----------------
__global__ __launch_bounds__(256, 2) void attn(const short* __restrict__ q,
                                               const short* __restrict__ k,
                                               const short* __restrict__ vt,
                                               float* __restrict__ out) {
    __shared__ short Ks[128 * 64];      // [key][d], 16B slot = chunk ^ (key&7)
    __shared__ short Vs[64 * 128];      // [d][key], 16B slot = (c&8)|((c^(d&7))&7)
    __shared__ short Ps[4 * 32 * 136];  // per-wave P [qrow 0..31][key], stride 136 shorts

    int tid = threadIdx.x;
    int lane = tid & 63;
    int wid = tid >> 6;
    int l32 = lane & 31;
    int half = lane >> 5;

    int flat = blockIdx.x;
    int xcd = flat & 7;
    int slot = flat >> 3;
    int bh = xcd * 8 + (slot >> 3);
    int qx = slot & 7;
    int b = bh >> 4, h = bh & 15;

    const short* qp = q + (size_t)(b * 16 + h) * 2048 * 64;
    const short* kp = k + (size_t)(b * 16 + h) * 2048 * 64;
    const short* vp = vt + (size_t)(b * 16 + h) * 64 * 2048;

    int krow = tid >> 3;
    int ksw = ((tid & 7) ^ (krow & 7)) * 8;
    int vd = tid >> 4;
    int vc = tid & 15;
    int vsw = ((vc & 8) | ((vc ^ vd) & 7)) * 8;

    short* pw = Ps + wid * (32 * 136);

    for (int phase = 0; phase < 2; phase++) {
        int qt = (phase == 0) ? qx : (15 - qx);
        int qbase = qt * 128;
        int qrow_w = qbase + wid * 32;
        int qlane = qrow_w + l32;

        short8 qf[4];
#pragma unroll
        for (int s = 0; s < 4; s++)
            qf[s] = *(const short8*)(qp + (size_t)qlane * 64 + s * 16 + half * 8);

        floatx16 oacc[2];
#pragma unroll
        for (int nt = 0; nt < 2; nt++)
#pragma unroll
            for (int e = 0; e < 16; e++) oacc[nt][e] = 0.f;
        float rs = 0.f;

        int ntiles = qt + 1;
        for (int t = 0; t < ntiles; t++) {
            int kvb = t * 128;
            __syncthreads();
#pragma unroll
            for (int l = 0; l < 4; l++) {
                const short* g = kp + (size_t)(kvb + krow + l * 32) * 64 + ksw;
                __builtin_amdgcn_global_load_lds((const GLOBAL_AS void*)g,
                                                 (LDS_AS void*)(Ks + tid * 8 + l * 2048), 16, 0, 0);
            }
#pragma unroll
            for (int l = 0; l < 4; l++) {
                const short* g = vp + (size_t)(vd + l * 16) * 2048 + kvb + vsw;
                __builtin_amdgcn_global_load_lds((const GLOBAL_AS void*)g,
                                                 (LDS_AS void*)(Vs + tid * 8 + l * 2048), 16, 0, 0);
            }
            __syncthreads();

            // ---- S^T[key][q] = K * Q^T ----
            floatx16 sacc[4];
#pragma unroll
            for (int kb = 0; kb < 4; kb++)
#pragma unroll
                for (int e = 0; e < 16; e++) sacc[kb][e] = 0.f;
#pragma unroll
            for (int s = 0; s < 4; s++) {
#pragma unroll
                for (int kb = 0; kb < 4; kb++) {
                    int key = kb * 32 + l32;
                    int c = s * 2 + half;
                    short8 kf = *(const short8*)(Ks + key * 64 + ((c ^ (key & 7)) * 8));
                    sacc[kb] = __builtin_amdgcn_mfma_f32_32x32x16_bf16(kf, qf[s], sacc[kb], 0, 0, 0);
                }
            }

            // ---- exp2 + mask (diag tile only) + local row-sum + packed P write ----
            bool diag = (t == ntiles - 1);
#pragma unroll
            for (int kb = 0; kb < 4; kb++) {
#pragma unroll
                for (int e = 0; e < 16; e++) {
                    float p = __builtin_amdgcn_exp2f(sacc[kb][e]);
                    if (diag) {
                        int key = kvb + kb * 32 + (e & 3) + 8 * (e >> 2) + 4 * half;
                        p = (key > qlane) ? 0.f : p;
                    }
                    sacc[kb][e] = p;
                    rs += p;
                }
#pragma unroll
                for (int g = 0; g < 4; g++) {
                    int2 wv;
                    wv.x = pk2(sacc[kb][4 * g], sacc[kb][4 * g + 1]);
                    wv.y = pk2(sacc[kb][4 * g + 2], sacc[kb][4 * g + 3]);
                    *(int2*)(pw + l32 * 136 + kb * 32 + g * 8 + 4 * half) = wv;
                }
            }
            __threadfence_block();

            // ---- O^T += V^T * P^T ----
#pragma unroll
            for (int s = 0; s < 8; s++) {
                short8 pf = *(const short8*)(pw + l32 * 136 + s * 16 + half * 8);
#pragma unroll
                for (int nt = 0; nt < 2; nt++) {
                    int d = nt * 32 + l32;
                    int c = s * 2 + half;
                    int sl = (c & 8) | ((c ^ (d & 7)) & 7);
                    short8 vf = *(const short8*)(Vs + d * 128 + sl * 8);
                    oacc[nt] = __builtin_amdgcn_mfma_f32_32x32x16_bf16(vf, pf, oacc[nt], 0, 0, 0);
                }
            }
        }

        // ---- epilogue: lane owns q; local normalize, float4 stores ----
        float tot = rs + __shfl_xor(rs, 32);
        float inv = 1.0f / tot;
        float* orow = out + ((size_t)b * 2048 + qlane) * 1024 + h * 64;
#pragma unroll
        for (int nt = 0; nt < 2; nt++) {
#pragma unroll
            for (int g = 0; g < 4; g++) {
                float4 o4;
                o4.x = oacc[nt][4 * g + 0] * inv;
                o4.y = oacc[nt][4 * g + 1] * inv;
                o4.z = oacc[nt][4 * g + 2] * inv;
                o4.w = oacc[nt][4 * g + 3] * inv;
                *(float4*)(orow + nt * 32 + 8 * g + 4 * half) = o4;
            }
        }
    }
}

extern "C" void kernel_launch(void* const* d_in, const int* in_sizes, int n_in,
                              void* d_out, int out_size, void* d_ws, size_t ws_size,
                              hipStream_t stream) {
    const float* x = (const float*)d_in[0];
    const float* Wq = (const float*)d_in[1];
    const float* Wk = (const float*)d_in[2];
    const float* Wv = (const float*)d_in[3];
    float* out = (float*)d_out;
    char* ws = (char*)d_ws;

    short* wb = (short*)(ws + (16u << 20));          //  6 MB: [3,1024,1024] bf16
    short* qb = (short*)(ws + (22u << 20));          // 16 MB: [4,16,2048,64]
    short* kb = (short*)(ws + (38u << 20));          // 16 MB: [4,16,2048,64]
    short* vtb = (short*)(ws + (54u << 20));         // 16 MB: [4,16,64,2048]

    cast_w<<<3 * 1024, 256, 0, stream>>>(Wq, Wk, Wv, wb);
    qkv_gemm<<<dim3(64, 8, 3), 256, 0, stream>>>(x, wb, qb, kb, vtb);
    attn<<<512, 256, 0, stream>>>(qb, kb, vtb, out);
}

// Round 8
// 209.407 us; speedup vs baseline: 1.0518x; 1.0518x over previous
//
#include <hip/hip_runtime.h>

typedef __attribute__((ext_vector_type(8))) short short8;
typedef __attribute__((ext_vector_type(4))) short short4v;
typedef __attribute__((ext_vector_type(4))) float floatx4;
typedef __attribute__((ext_vector_type(16))) float floatx16;

#define GLOBAL_AS __attribute__((address_space(1)))
#define LDS_AS __attribute__((address_space(3)))

__device__ __forceinline__ short f2bs(float f) {
    // RNE float -> bf16 (as short). Inputs finite here.
    union { float f; unsigned u; } v; v.f = f;
    unsigned r = v.u + 0x7fffu + ((v.u >> 16) & 1u);
    return (short)(r >> 16);
}

#if __has_builtin(__builtin_amdgcn_cvt_pk_bf16_f32)
typedef __attribute__((ext_vector_type(2))) __bf16 bf16x2;
__device__ __forceinline__ unsigned pk2(float a, float b) {
    union { bf16x2 v; unsigned u; } u;
    u.v = __builtin_amdgcn_cvt_pk_bf16_f32(a, b);
    return u.u;
}
#else
__device__ __forceinline__ unsigned pk2(float a, float b) {
    union { float f; unsigned u; } x, y; x.f = a; y.f = b;
    return ((y.u + 0x8000u) & 0xffff0000u) | ((x.u + 0x8000u) >> 16);
}
#endif

// ---------------- fused cast fp32 -> bf16 (x + Wq + Wk + Wv) ----------------
__global__ __launch_bounds__(256) void cast_all(const float* __restrict__ x,
                                                const float* __restrict__ Wq,
                                                const float* __restrict__ Wk,
                                                const float* __restrict__ Wv,
                                                short* __restrict__ xb,
                                                short* __restrict__ wb) {
    int b = blockIdx.x;
    int t = threadIdx.x;
    const float* src;
    short* dst;
    int idx;
    if (b < 8192) {
        src = x; dst = xb; idx = b * 1024 + t * 4;
    } else {
        int r = b - 8192;
        int wz = r >> 10;
        src = (wz == 0) ? Wq : (wz == 1) ? Wk : Wv;
        dst = wb + wz * (1 << 20);
        idx = (r & 1023) * 1024 + t * 4;
    }
    float4 v = *(const float4*)(src + idx);
    short4v o;
    o.x = f2bs(v.x); o.y = f2bs(v.y); o.z = f2bs(v.z); o.w = f2bs(v.w);
    *(short4v*)(dst + idx) = o;
}

// ---------------- QKV GEMM: P = xb @ W^T, BK=64 (R5 exact) ----------------
// z=0 -> Q [b,h,n,d] pre-scaled by 0.125*log2(e); z=1 -> K [b,h,n,d]; z=2 -> V^T [b,h,d,n]
__global__ __launch_bounds__(256) void qkv_gemm(const short* __restrict__ xb,
                                                const short* __restrict__ wb,
                                                short* __restrict__ qout,
                                                short* __restrict__ kout,
                                                short* __restrict__ vtout) {
    __shared__ short As[128 * 64];  // [m][k], 16B chunks XOR-swizzled: slot = chunk ^ (row&7)
    __shared__ short Bs[128 * 64];
    const int K = 1024;
    int tid = threadIdx.x;
    int lane = tid & 63;
    int wid = tid >> 6;
    int quad = lane >> 4;
    int l16 = lane & 15;
    int wm = (wid >> 1) * 64;
    int wn = (wid & 1) * 64;
    int bm = blockIdx.x * 128;
    int bn = blockIdx.y * 128;
    const short* W = wb + (size_t)blockIdx.z * K * 1024;

    floatx4 acc[4][4];
#pragma unroll
    for (int i = 0; i < 4; i++)
#pragma unroll
        for (int j = 0; j < 4; j++) acc[i][j] = (floatx4){0.f, 0.f, 0.f, 0.f};

    int srow = tid >> 3;
    int ssw = ((tid & 7) ^ (srow & 7)) * 8;

    for (int kk = 0; kk < K; kk += 64) {
        __syncthreads();
#pragma unroll
        for (int l = 0; l < 4; l++) {
            const short* g = xb + (size_t)(bm + srow + l * 32) * K + kk + ssw;
            __builtin_amdgcn_global_load_lds((const GLOBAL_AS void*)g,
                                             (LDS_AS void*)(As + tid * 8 + l * 2048), 16, 0, 0);
        }
#pragma unroll
        for (int l = 0; l < 4; l++) {
            const short* g = W + (size_t)(bn + srow + l * 32) * K + kk + ssw;
            __builtin_amdgcn_global_load_lds((const GLOBAL_AS void*)g,
                                             (LDS_AS void*)(Bs + tid * 8 + l * 2048), 16, 0, 0);
        }
        __syncthreads();

#pragma unroll
        for (int s = 0; s < 2; s++) {
            int slot = ((s * 4 + quad) ^ (l16 & 7)) * 8;
            short8 af[4], bf[4];
#pragma unroll
            for (int i = 0; i < 4; i++)
                af[i] = *(const short8*)(As + (wm + i * 16 + l16) * 64 + slot);
#pragma unroll
            for (int j = 0; j < 4; j++)
                bf[j] = *(const short8*)(Bs + (wn + j * 16 + l16) * 64 + slot);
#pragma unroll
            for (int i = 0; i < 4; i++)
#pragma unroll
                for (int j = 0; j < 4; j++)
                    acc[i][j] = __builtin_amdgcn_mfma_f32_16x16x32_bf16(af[i], bf[j], acc[i][j], 0, 0, 0);
        }
    }

    // Epilogue. C/D: col = l16, row = quad*4 + r.
    if (blockIdx.z == 2) {
        // V^T [b,h,d,n]: reg-quad = 4 consecutive seq -> packed b64 stores
#pragma unroll
        for (int i = 0; i < 4; i++) {
#pragma unroll
            for (int j = 0; j < 4; j++) {
                int m = bm + wm + i * 16 + quad * 4;
                int c = bn + wn + j * 16 + l16;
                int b = m >> 11, nn = m & 2047, h = c >> 6, dd = c & 63;
                int2 wv;
                wv.x = pk2(acc[i][j][0], acc[i][j][1]);
                wv.y = pk2(acc[i][j][2], acc[i][j][3]);
                *(int2*)(vtout + ((size_t)(b * 16 + h) * 64 + dd) * 2048 + nn) = wv;
            }
        }
    } else {
        // Q/K [b,h,n,d]: 16-lane-contiguous u16 stores (coalesced 32B segments beat packed-scattered)
        short* dst = (blockIdx.z == 0) ? qout : kout;
        float qs = (blockIdx.z == 0) ? 0.180336881f : 1.0f;  // 0.125*log2(e) folded into Q
#pragma unroll
        for (int i = 0; i < 4; i++) {
#pragma unroll
            for (int j = 0; j < 4; j++) {
#pragma unroll
                for (int r = 0; r < 4; r++) {
                    int m = bm + wm + i * 16 + quad * 4 + r;
                    int c = bn + wn + j * 16 + l16;
                    dst[((size_t)((m >> 11) * 16 + (c >> 6)) * 2048 + (m & 2047)) * 64 + (c & 63)] =
                        f2bs(acc[i][j][r] * qs);
                }
            }
        }
    }
}

// ---------------- Flash attention: 32x32x16 MFMA, S^T + O^T, chunked P (LDS 50KB) ----------------
// q: pre-scaled bf16 [b,h,2048,64]; k: [b,h,2048,64]; vt: [b,h,64,2048]; out fp32 [b,2048,1024]
// Block = 256 thr (4 waves x 32 qrows = 128-row Q tile). Pair (qx,15-qx) -> 17 KV-128 tiles.
// 512 blocks, XCD-swizzled. PV done in two 64-key chunks so Ps is half-size -> 3 blocks/CU.
__global__ __launch_bounds__(256, 3) void attn(const short* __restrict__ q,
                                               const short* __restrict__ k,
                                               const short* __restrict__ vt,
                                               float* __restrict__ out) {
    __shared__ short Ks[128 * 64];     // [key][d], 16B slot = chunk ^ (key&7)
    __shared__ short Vs[64 * 128];     // [d][key], 16B slot = (c&8)|((c^(d&7))&7)
    __shared__ short Ps[4 * 32 * 72];  // per-wave P chunk [qrow 0..31][key 0..63], stride 72

    int tid = threadIdx.x;
    int lane = tid & 63;
    int wid = tid >> 6;
    int l32 = lane & 31;
    int half = lane >> 5;

    int flat = blockIdx.x;
    int xcd = flat & 7;
    int slot = flat >> 3;
    int bh = xcd * 8 + (slot >> 3);
    int qx = slot & 7;
    int b = bh >> 4, h = bh & 15;

    const short* qp = q + (size_t)(b * 16 + h) * 2048 * 64;
    const short* kp = k + (size_t)(b * 16 + h) * 2048 * 64;
    const short* vp = vt + (size_t)(b * 16 + h) * 64 * 2048;

    int krow = tid >> 3;
    int ksw = ((tid & 7) ^ (krow & 7)) * 8;
    int vd = tid >> 4;
    int vc = tid & 15;
    int vsw = ((vc & 8) | ((vc ^ vd) & 7)) * 8;

    short* pw = Ps + wid * (32 * 72);

    for (int phase = 0; phase < 2; phase++) {
        int qt = (phase == 0) ? qx : (15 - qx);
        int qbase = qt * 128;
        int qrow_w = qbase + wid * 32;
        int qlane = qrow_w + l32;

        short8 qf[4];
#pragma unroll
        for (int s = 0; s < 4; s++)
            qf[s] = *(const short8*)(qp + (size_t)qlane * 64 + s * 16 + half * 8);

        floatx16 oacc[2];
#pragma unroll
        for (int nt = 0; nt < 2; nt++)
#pragma unroll
            for (int e = 0; e < 16; e++) oacc[nt][e] = 0.f;
        float rs = 0.f;

        int ntiles = qt + 1;
        for (int t = 0; t < ntiles; t++) {
            int kvb = t * 128;
            __syncthreads();
#pragma unroll
            for (int l = 0; l < 4; l++) {
                const short* g = kp + (size_t)(kvb + krow + l * 32) * 64 + ksw;
                __builtin_amdgcn_global_load_lds((const GLOBAL_AS void*)g,
                                                 (LDS_AS void*)(Ks + tid * 8 + l * 2048), 16, 0, 0);
            }
#pragma unroll
            for (int l = 0; l < 4; l++) {
                const short* g = vp + (size_t)(vd + l * 16) * 2048 + kvb + vsw;
                __builtin_amdgcn_global_load_lds((const GLOBAL_AS void*)g,
                                                 (LDS_AS void*)(Vs + tid * 8 + l * 2048), 16, 0, 0);
            }
            __syncthreads();

            // ---- S^T[key][q] = K * Q^T ----
            floatx16 sacc[4];
#pragma unroll
            for (int kb = 0; kb < 4; kb++)
#pragma unroll
                for (int e = 0; e < 16; e++) sacc[kb][e] = 0.f;
#pragma unroll
            for (int s = 0; s < 4; s++) {
#pragma unroll
                for (int kb = 0; kb < 4; kb++) {
                    int key = kb * 32 + l32;
                    int c = s * 2 + half;
                    short8 kf = *(const short8*)(Ks + key * 64 + ((c ^ (key & 7)) * 8));
                    sacc[kb] = __builtin_amdgcn_mfma_f32_32x32x16_bf16(kf, qf[s], sacc[kb], 0, 0, 0);
                }
            }

            // ---- two 64-key chunks: exp2+mask+P-write, fence, PV ----
            bool diag = (t == ntiles - 1);
#pragma unroll
            for (int ch = 0; ch < 2; ch++) {
#pragma unroll
                for (int kbl = 0; kbl < 2; kbl++) {
                    int kb = ch * 2 + kbl;
#pragma unroll
                    for (int e = 0; e < 16; e++) {
                        float p = __builtin_amdgcn_exp2f(sacc[kb][e]);
                        if (diag) {
                            int key = kvb + kb * 32 + (e & 3) + 8 * (e >> 2) + 4 * half;
                            p = (key > qlane) ? 0.f : p;
                        }
                        sacc[kb][e] = p;
                        rs += p;
                    }
#pragma unroll
                    for (int g = 0; g < 4; g++) {
                        int2 wv;
                        wv.x = pk2(sacc[kb][4 * g], sacc[kb][4 * g + 1]);
                        wv.y = pk2(sacc[kb][4 * g + 2], sacc[kb][4 * g + 3]);
                        *(int2*)(pw + l32 * 72 + kbl * 32 + g * 8 + 4 * half) = wv;
                    }
                }
                __threadfence_block();

                // ---- O^T += V^T * P^T over this chunk's 64 keys ----
#pragma unroll
                for (int sl = 0; sl < 4; sl++) {
                    int s = ch * 4 + sl;
                    short8 pf = *(const short8*)(pw + l32 * 72 + sl * 16 + half * 8);
#pragma unroll
                    for (int nt = 0; nt < 2; nt++) {
                        int d = nt * 32 + l32;
                        int c = s * 2 + half;
                        int sl2 = (c & 8) | ((c ^ (d & 7)) & 7);
                        short8 vf = *(const short8*)(Vs + d * 128 + sl2 * 8);
                        oacc[nt] = __builtin_amdgcn_mfma_f32_32x32x16_bf16(vf, pf, oacc[nt], 0, 0, 0);
                    }
                }
                __threadfence_block();
            }
        }

        // ---- epilogue: lane owns q; local normalize, float4 stores ----
        float tot = rs + __shfl_xor(rs, 32);
        float inv = 1.0f / tot;
        float* orow = out + ((size_t)b * 2048 + qlane) * 1024 + h * 64;
#pragma unroll
        for (int nt = 0; nt < 2; nt++) {
#pragma unroll
            for (int g = 0; g < 4; g++) {
                float4 o4;
                o4.x = oacc[nt][4 * g + 0] * inv;
                o4.y = oacc[nt][4 * g + 1] * inv;
                o4.z = oacc[nt][4 * g + 2] * inv;
                o4.w = oacc[nt][4 * g + 3] * inv;
                *(float4*)(orow + nt * 32 + 8 * g + 4 * half) = o4;
            }
        }
    }
}

extern "C" void kernel_launch(void* const* d_in, const int* in_sizes, int n_in,
                              void* d_out, int out_size, void* d_ws, size_t ws_size,
                              hipStream_t stream) {
    const float* x = (const float*)d_in[0];
    const float* Wq = (const float*)d_in[1];
    const float* Wk = (const float*)d_in[2];
    const float* Wv = (const float*)d_in[3];
    float* out = (float*)d_out;
    char* ws = (char*)d_ws;

    short* xb = (short*)ws;                          // 16 MB: [8192,1024] bf16
    short* wb = (short*)(ws + (16u << 20));          //  6 MB: [3,1024,1024] bf16
    short* qb = (short*)(ws + (22u << 20));          // 16 MB: [4,16,2048,64]
    short* kb = (short*)(ws + (38u << 20));          // 16 MB: [4,16,2048,64]
    short* vtb = (short*)(ws + (54u << 20));         // 16 MB: [4,16,64,2048]

    cast_all<<<8192 + 3 * 1024, 256, 0, stream>>>(x, Wq, Wk, Wv, xb, wb);
    qkv_gemm<<<dim3(64, 8, 3), 256, 0, stream>>>(xb, wb, qb, kb, vtb);
    attn<<<512, 256, 0, stream>>>(qb, kb, vtb, out);
}